// Round 5
// baseline (390.227 us; speedup 1.0000x reference)
//
#include <hip/hip_runtime.h>
#include <math.h>

#define B_ 64
#define T_ 1024
#define D_ 512
#define U_ 1024

typedef __bf16 bf16x8 __attribute__((ext_vector_type(8)));
typedef float f32x16 __attribute__((ext_vector_type(16)));
typedef unsigned int u32;

__device__ __forceinline__ float fast_tanh(float x) {
    float ax = fabsf(x);
    float e = __expf(2.0f * ax);
    float r = 1.0f - __fdividef(2.0f, e + 1.0f);
    return copysignf(r, x);
}

__device__ __forceinline__ u32 f2bf_pk(float lo, float hi) {
    u32 a = __float_as_uint(lo) + 0x8000u;
    u32 b = __float_as_uint(hi) + 0x8000u;
    return (a >> 16) | (b & 0xffff0000u);
}

__device__ __forceinline__ void dma16(const void* g, void* l) {
    __builtin_amdgcn_global_load_lds(
        (const __attribute__((address_space(1))) u32*)g,
        (__attribute__((address_space(3))) u32*)l, 16, 0, 0);
}

// K0: W1 [D][U] fp32 -> W1T [U][D] bf16
__global__ __launch_bounds__(256) void w1t_kernel(
    const float* __restrict__ W1, unsigned short* __restrict__ W1T) {
    const int gidx = blockIdx.x * 256 + threadIdx.x;
    const int u  = gidx & (U_ - 1);
    const int d0 = (gidx >> 10) * 8;
    float f[8];
#pragma unroll
    for (int i = 0; i < 8; ++i) f[i] = W1[(size_t)(d0 + i) * U_ + u];
    uint4 w;
    w.x = f2bf_pk(f[0], f[1]);
    w.y = f2bf_pk(f[2], f[3]);
    w.z = f2bf_pk(f[4], f[5]);
    w.w = f2bf_pk(f[6], f[7]);
    *(uint4*)&W1T[(size_t)u * D_ + d0] = w;
}

// K1: ph[b][u] = hidden[b,:]·W2[:,u] + W2_b[u] + W1_b[u]; grid (U/256, B)
__global__ __launch_bounds__(256) void ph_kernel(
    const float* __restrict__ hidden, const float* __restrict__ W2,
    const float* __restrict__ W2b, const float* __restrict__ W1b,
    float* __restrict__ ph) {
    const int u = blockIdx.x * 256 + threadIdx.x;
    const int b = blockIdx.y;
    const float* h = hidden + b * D_;
    float acc = 0.f;
#pragma unroll 8
    for (int d = 0; d < D_; ++d) acc = fmaf(h[d], W2[(size_t)d * U_ + u], acc);
    ph[b * U_ + u] = acc + W2b[u] + W1b[u];
}

// K2: fused bf16 32x32x16-MFMA GEMM + tanh + V-dot -> lpart[uh][b][t]
// 512 thr / 8 waves; block tile 128 t x 256 u; u-split x4; wave 64x64 (2x2 of 32x32).
// ALL staging via global_load_lds (A as raw fp32, B as bf16 from W1T), issued at
// iter start -> no in-wave vmcnt dependencies; the only drain is the barrier,
// with a full iteration of slack. A fp32->bf16 convert happens at frag-read time.
// A LDS: row r (128B = 32 fp32), 16B chunk c stored at slot c^(r&7)
//   (source-side swizzle: lane reads chunk (l&7)^(l>>3) of row base+(l>>3))
//   -> coalesced 128B row segments on load, conflict-free b128 frag reads.
// B LDS: verified R3/R4 scheme (0 conflicts).
__global__ __launch_bounds__(512, 4) void logits_mfma_kernel(
    const float* __restrict__ feat,          // [B,T,D] fp32
    const unsigned short* __restrict__ W1T,  // [U,D] bf16
    const float* __restrict__ ph,            // [B,U] biases folded
    const float* __restrict__ Vw,            // [U]
    float* __restrict__ lpart) {             // [4][B][T]
    __shared__ __align__(16) float Asf[2][4096];  // 128 rows x 32 fp32 = 16 KB each
    __shared__ __align__(16) char  Bs[2][16384];  // 256 rows x 32 bf16

    const int tid  = threadIdx.x;
    const int gx   = blockIdx.x;       // uh fastest: A-sharing blocks co-dispatch
    const int uh   = gx & 3;
    const int tt   = gx >> 2;
    const int b    = blockIdx.y;
    const int t0   = tt * 128;
    const int uoff = uh * 256;
    const int lane = tid & 63;
    const int widx = tid >> 6;
    const int wm = widx >> 2, wn = widx & 3;
    const int l31 = lane & 31, g = lane >> 5;
    const int sw = (l31 >> 2) & 3;

    // A DMA source: lane -> row widx*16 + j*8 + (l>>3), chunk (l&7)^(l>>3)
    const int arw  = lane >> 3;                   // 0..7
    const int achk = (lane & 7) ^ arw;            // swizzled source 16B chunk
    const float* aSrcLane =
        feat + ((size_t)(b * T_ + t0 + widx * 16 + arw)) * D_ + achk * 4;

    // B DMA source (swizzle folded into source address) — verified R3/R4
    const int bq = (lane & 3) ^ ((lane >> 4) & 3);
    const unsigned short* bSrcLane =
        W1T + (size_t)(uoff + (lane >> 2)) * D_ + bq * 8;

    auto issueA = [&](int buf, int kc) {
#pragma unroll
        for (int j = 0; j < 2; ++j)
            dma16(aSrcLane + (size_t)j * 8 * D_ + kc,
                  &Asf[buf][(widx * 16 + j * 8) * 32]);
    };
    auto issueB = [&](int buf, int kc) {
#pragma unroll
        for (int j = 0; j < 2; ++j) {
            const int v = widx * 2 + j;   // 16 slots of 16 rows, wave-uniform
            dma16(bSrcLane + (size_t)v * 16 * D_ + kc, &Bs[buf][v * 1024]);
        }
    };
    // A fragment: read 2 swizzled b128 fp32 chunks, convert to bf16x8
    auto readA = [&](const float* Ab, int ks, int mt) -> bf16x8 {
        const int r  = wm * 64 + mt * 32 + l31;
        const int x  = r & 7;
        const int c0 = ks * 4 + g * 2;
        const float4 lo = *(const float4*)&Ab[r * 32 + (c0 ^ x) * 4];
        const float4 hi = *(const float4*)&Ab[r * 32 + ((c0 + 1) ^ x) * 4];
        uint4 p;
        p.x = f2bf_pk(lo.x, lo.y);
        p.y = f2bf_pk(lo.z, lo.w);
        p.z = f2bf_pk(hi.x, hi.y);
        p.w = f2bf_pk(hi.z, hi.w);
        return __builtin_bit_cast(bf16x8, p);
    };

    f32x16 acc[2][2];
#pragma unroll
    for (int mt = 0; mt < 2; ++mt)
#pragma unroll
        for (int nt = 0; nt < 2; ++nt) acc[mt][nt] = (f32x16)(0.f);

    issueA(0, 0);
    issueB(0, 0);
    __syncthreads();

    for (int kt = 0; kt < 16; ++kt) {
        const int cur = kt & 1, nxt = cur ^ 1;
        if (kt < 15) {                      // all vm ops at iter start
            issueA(nxt, (kt + 1) * 32);
            issueB(nxt, (kt + 1) * 32);
        }
        const float* Ab = Asf[cur];
        const char*  Bb = Bs[cur];
#pragma unroll
        for (int ks = 0; ks < 2; ++ks) {
            const int qsw = ((2 * ks + g) ^ sw) << 4;
            bf16x8 af[2], bfr[2];
#pragma unroll
            for (int mt = 0; mt < 2; ++mt) af[mt] = readA(Ab, ks, mt);
#pragma unroll
            for (int nt = 0; nt < 2; ++nt)
                bfr[nt] = *(const bf16x8*)(Bb + (wn * 64 + nt * 32 + l31) * 64 + qsw);
#pragma unroll
            for (int mt = 0; mt < 2; ++mt)
#pragma unroll
                for (int nt = 0; nt < 2; ++nt)
                    acc[mt][nt] = __builtin_amdgcn_mfma_f32_32x32x16_bf16(
                        af[mt], bfr[nt], acc[mt][nt], 0, 0, 0);
        }
        __syncthreads();
    }

    // fused epilogue: tanh + V-dot, reduce over u (verified R3/R4)
    float lp[2][16];
#pragma unroll
    for (int mt = 0; mt < 2; ++mt)
#pragma unroll
        for (int r = 0; r < 16; ++r) lp[mt][r] = 0.f;

#pragma unroll
    for (int nt = 0; nt < 2; ++nt) {
        const int u = uoff + wn * 64 + nt * 32 + l31;
        const float phv = ph[b * U_ + u];
        const float vw  = Vw[u];
#pragma unroll
        for (int mt = 0; mt < 2; ++mt)
#pragma unroll
            for (int r = 0; r < 16; ++r)
                lp[mt][r] = fmaf(vw, fast_tanh(acc[mt][nt][r] + phv), lp[mt][r]);
    }
#pragma unroll
    for (int mt = 0; mt < 2; ++mt)
#pragma unroll
        for (int r = 0; r < 16; ++r) {
            float v = lp[mt][r];
            v += __shfl_xor(v, 1);
            v += __shfl_xor(v, 2);
            v += __shfl_xor(v, 4);
            v += __shfl_xor(v, 8);
            v += __shfl_xor(v, 16);
            lp[mt][r] = v;
        }
    __syncthreads();
    float* scr = (float*)&Asf[0][0];   // [128 rows][4 wn]
    if (l31 == 0) {
#pragma unroll
        for (int mt = 0; mt < 2; ++mt)
#pragma unroll
            for (int r = 0; r < 16; ++r) {
                const int row = wm * 64 + mt * 32 + (r & 3) + 8 * (r >> 2) + 4 * g;
                scr[row * 4 + wn] = lp[mt][r];
            }
    }
    __syncthreads();
    if (tid < 128) {
        const float s = scr[tid * 4 + 0] + scr[tid * 4 + 1] +
                        scr[tid * 4 + 2] + scr[tid * 4 + 3];
        lpart[((size_t)uh * B_ + b) * T_ + t0 + tid] = s;
    }
}

// K3: softmax over T from 4 u-quarter partials (Vb cancels)
__global__ __launch_bounds__(256) void softmax4_kernel(
    const float* __restrict__ lp, float* __restrict__ attn) {
    const int b = blockIdx.x;
    const int tid = threadIdx.x;
    __shared__ float redm[4];
    __shared__ float reds[4];
    float v[4];
    float mx = -3.4e38f;
#pragma unroll
    for (int j = 0; j < 4; ++j) {
        const int x = b * T_ + tid + 256 * j;
        v[j] = lp[x] + lp[B_ * T_ + x] + lp[2 * B_ * T_ + x] + lp[3 * B_ * T_ + x];
        mx = fmaxf(mx, v[j]);
    }
#pragma unroll
    for (int off = 32; off > 0; off >>= 1) mx = fmaxf(mx, __shfl_xor(mx, off));
    if ((tid & 63) == 0) redm[tid >> 6] = mx;
    __syncthreads();
    mx = fmaxf(fmaxf(redm[0], redm[1]), fmaxf(redm[2], redm[3]));
    float s = 0.f;
#pragma unroll
    for (int j = 0; j < 4; ++j) {
        v[j] = __expf(v[j] - mx);
        s += v[j];
    }
#pragma unroll
    for (int off = 32; off > 0; off >>= 1) s += __shfl_xor(s, off);
    if ((tid & 63) == 0) reds[tid >> 6] = s;
    __syncthreads();
    s = reds[0] + reds[1] + reds[2] + reds[3];
    const float inv = 1.0f / s;
#pragma unroll
    for (int j = 0; j < 4; ++j) attn[b * T_ + tid + 256 * j] = v[j] * inv;
}

// K4: context partials, float4, 16 t-segments. grid (8, B), block 256
__global__ __launch_bounds__(256) void context_partial_kernel(
    const float* __restrict__ feat, const float* __restrict__ attn,
    float* __restrict__ part) {
    const int b   = blockIdx.y;
    const int seg = blockIdx.x;
    const int d4  = (threadIdx.x & 127) * 4;
    const int h   = threadIdx.x >> 7;
    const int t0  = seg * 128 + h * 64;
    const float* fb = feat + ((size_t)b * T_ + t0) * D_ + d4;
    const float* wb = attn + b * T_ + t0;
    float4 acc = {0.f, 0.f, 0.f, 0.f};
#pragma unroll 4
    for (int t = 0; t < 64; ++t) {
        const float w  = wb[t];
        const float4 f = *(const float4*)&fb[(size_t)t * D_];
        acc.x = fmaf(w, f.x, acc.x);
        acc.y = fmaf(w, f.y, acc.y);
        acc.z = fmaf(w, f.z, acc.z);
        acc.w = fmaf(w, f.w, acc.w);
    }
    *(float4*)&part[((size_t)(b * 16 + seg * 2 + h)) * D_ + d4] = acc;
}

// K5: reduce 16 partials -> context. grid (B*D/256)
__global__ __launch_bounds__(256) void context_reduce_kernel(
    const float* __restrict__ part, float* __restrict__ ctx) {
    const int i = blockIdx.x * 256 + threadIdx.x;
    const int b = i >> 9;
    const int d = i & (D_ - 1);
    float s = 0.f;
#pragma unroll
    for (int g = 0; g < 16; ++g) s += part[((size_t)(b * 16 + g)) * D_ + d];
    ctx[i] = s;
}

extern "C" void kernel_launch(void* const* d_in, const int* in_sizes, int n_in,
                              void* d_out, int out_size, void* d_ws, size_t ws_size,
                              hipStream_t stream) {
    const float* feat   = (const float*)d_in[0];
    const float* hidden = (const float*)d_in[1];
    const float* W1w    = (const float*)d_in[2];
    const float* W1b    = (const float*)d_in[3];
    const float* W2w    = (const float*)d_in[4];
    const float* W2b    = (const float*)d_in[5];
    const float* Vw     = (const float*)d_in[6];
    // V_b cancels in softmax and doesn't affect context.

    float* out_ctx  = (float*)d_out;             // [B,D]
    float* out_attn = out_ctx + B_ * D_;         // [B,T]

    unsigned short* W1T = (unsigned short*)d_ws;             // U*D bf16 = 1 MB
    float* ph     = (float*)(W1T + (size_t)U_ * D_);         // B*U
    float* lpart  = ph + B_ * U_;                            // 4*B*T
    float* part   = lpart + 4 * B_ * T_;                     // B*16*D

    w1t_kernel<<<256, 256, 0, stream>>>(W1w, W1T);
    ph_kernel<<<dim3(U_ / 256, B_), 256, 0, stream>>>(hidden, W2w, W2b, W1b, ph);
    logits_mfma_kernel<<<dim3(32, B_), 512, 0, stream>>>(feat, W1T, ph, Vw, lpart);
    softmax4_kernel<<<B_, 256, 0, stream>>>(lpart, out_attn);
    context_partial_kernel<<<dim3(8, B_), 256, 0, stream>>>(feat, out_attn, part);
    context_reduce_kernel<<<B_ * D_ / 256, 256, 0, stream>>>(part, out_ctx);
}